// Round 8
// baseline (89.096 us; speedup 1.0000x reference)
//
#include <hip/hip_runtime.h>
#include <hip/hip_bf16.h>

// Problem constants
#define B_ 4
#define S_ 2048
#define E_ 1024

// K1 tiling
#define ES 32                 // e-slices of 32
#define SC 4                  // s-chunks of 512
#define EPS 32                // e's per slice
#define SPC 512               // rows per s-chunk
#define NPART (ES * SC)       // 128 t-partials per batch

// K2 roles
#define MIDB 256              // mid-role blocks (64 jb x 4 b)
#define BCB  1024             // bcast-role blocks (256 sb x 4 b)
#define RPB 8                 // rows per bcast block

// Module-scope state: zero-initialized at module load, reset by the kernel
// itself at the end of every launch (last-reader protocol) -> replay-safe,
// no memset node needed.
__device__ float g_o[B_][E_];
__device__ int   g_prog[B_];
__device__ int   g_rdr[B_];

// ---------------------------------------------------------------------------
// K1: fused colsum + GEMV1 split-k (round-6 pattern, retiled to 2 blocks/CU).
// Block (es, sc, b), 512 threads:
//   vb[32] = colsum over 512 rows of value[b][s][e-slice]
//   tpart[es*SC+sc][b][j] = sum_{e in slice} vb[e] * Wv[e][j]   (plain store)
// grid (ES, SC, B_) = 512 blocks, 512 threads.
// ---------------------------------------------------------------------------
__global__ __launch_bounds__(512) void k_front(const float* __restrict__ value,
                                               const float* __restrict__ Wv,
                                               float* __restrict__ tpart) {
    const int es = blockIdx.x, sc = blockIdx.y, b = blockIdx.z;
    const int t = threadIdx.x;
    __shared__ float4 red[64][8];
    __shared__ float vb[EPS];

    // Phase A: column-sum the [512 s][32 e] tile.
    {
        const int c4 = t & 7, rg = t >> 3;
        const float* base = value + ((size_t)b * S_ + (size_t)sc * SPC) * E_
                            + es * EPS + c4 * 4;
        float4 acc = make_float4(0.f, 0.f, 0.f, 0.f);
#pragma unroll
        for (int r = 0; r < 8; ++r) {
            float4 v = *reinterpret_cast<const float4*>(base + (size_t)(rg + r * 64) * E_);
            acc.x += v.x; acc.y += v.y; acc.z += v.z; acc.w += v.w;
        }
        red[rg][c4] = acc;
    }
    __syncthreads();
    if (t < 8) {
        float4 s = make_float4(0.f, 0.f, 0.f, 0.f);
        for (int g = 0; g < 64; ++g) {
            float4 v = red[g][t];
            s.x += v.x; s.y += v.y; s.z += v.z; s.w += v.w;
        }
        reinterpret_cast<float4*>(vb)[t] = s;
    }
    __syncthreads();

    // Phase B: t-partial over the 32 Wv rows of this slice; j = t, t+512.
    {
        const float* wv = Wv + (size_t)(es * EPS) * E_;
        float a0 = 0.f, a1 = 0.f;
#pragma unroll
        for (int k = 0; k < EPS; ++k) {
            const float vk = vb[k];
            a0 = fmaf(vk, wv[(size_t)k * E_ + t], a0);
            a1 = fmaf(vk, wv[(size_t)k * E_ + t + 512], a1);
        }
        const int p = es * SC + sc;
        float* dst = tpart + ((size_t)p * B_ + b) * E_;
        dst[t] = a0;
        dst[t + 512] = a1;
    }
}

// ---------------------------------------------------------------------------
// K2: mid role (blocks 0..255) + bcast role (blocks 256..1279), one kernel.
// mid (jb,b): tj = S*bv + sum_p tpart[p][b][jb*16..+16];
//             g_o[b][:] += tj @ Wo[jb*16..+16,:]; bump g_prog[b].
// bcast (sb,b): spin g_prog[b]==64; out rows = g_o[b] + bo.
// Last reader per b zeroes g_o[b] and resets counters (replay-safe).
// ---------------------------------------------------------------------------
__global__ __launch_bounds__(256) void k_back(const float* __restrict__ tpart,
                                              const float* __restrict__ bv,
                                              const float* __restrict__ Wo,
                                              const float* __restrict__ bo,
                                              float* __restrict__ out) {
    const int bid = blockIdx.x;
    const int t = threadIdx.x;

    if (bid < MIDB) {
        // ---------------- mid role ----------------
        const int jb = bid & 63, b = bid >> 6;
        __shared__ float red[16][16];
        __shared__ float tj[16];

        {
            const int jl = t & 15, pg = t >> 4;
            float s = 0.f;
#pragma unroll
            for (int q = 0; q < 8; ++q)
                s += tpart[((size_t)(pg + q * 16) * B_ + b) * E_ + jb * 16 + jl];
            red[pg][jl] = s;
        }
        __syncthreads();
        if (t < 16) {
            float v = (float)S_ * bv[jb * 16 + t];
#pragma unroll
            for (int g = 0; g < 16; ++g) v += red[g][t];
            tj[t] = v;
        }
        __syncthreads();

        float oacc[4] = {0.f, 0.f, 0.f, 0.f};
#pragma unroll
        for (int jj = 0; jj < 16; ++jj) {
            const float* wo = Wo + (size_t)(jb * 16 + jj) * E_;
            const float tv = tj[jj];
#pragma unroll
            for (int k2 = 0; k2 < 4; ++k2)
                oacc[k2] = fmaf(tv, wo[k2 * 256 + t], oacc[k2]);
        }
#pragma unroll
        for (int k2 = 0; k2 < 4; ++k2)
            atomicAdd(&g_o[b][k2 * 256 + t], oacc[k2]);

        __threadfence();          // drain RMWs before publishing progress
        __syncthreads();
        if (t == 0) atomicAdd(&g_prog[b], 1);
    } else {
        // ---------------- bcast role ----------------
        const int id = bid - MIDB;
        const int sb = id & 255, b = id >> 8;
        __shared__ int lastflag;

        if (t == 0) {
            while (__hip_atomic_load(&g_prog[b], __ATOMIC_RELAXED,
                                     __HIP_MEMORY_SCOPE_AGENT) < 64)
                __builtin_amdgcn_s_sleep(16);
        }
        __syncthreads();

        // Read o via agent-scope (coherent) loads; add bo.
        float o0 = __hip_atomic_load(&g_o[b][t * 4 + 0], __ATOMIC_RELAXED, __HIP_MEMORY_SCOPE_AGENT);
        float o1 = __hip_atomic_load(&g_o[b][t * 4 + 1], __ATOMIC_RELAXED, __HIP_MEMORY_SCOPE_AGENT);
        float o2 = __hip_atomic_load(&g_o[b][t * 4 + 2], __ATOMIC_RELAXED, __HIP_MEMORY_SCOPE_AGENT);
        float o3 = __hip_atomic_load(&g_o[b][t * 4 + 3], __ATOMIC_RELAXED, __HIP_MEMORY_SCOPE_AGENT);
        float4 bb = reinterpret_cast<const float4*>(bo)[t];
        float4 ov = make_float4(o0 + bb.x, o1 + bb.y, o2 + bb.z, o3 + bb.w);

        float4* dst = reinterpret_cast<float4*>(
            out + ((size_t)b * S_ + (size_t)sb * RPB) * E_);
#pragma unroll
        for (int r = 0; r < RPB; ++r)
            dst[r * (E_ / 4) + t] = ov;

        __syncthreads();          // all threads' g_o loads are complete
        if (t == 0) {
            int old = __hip_atomic_fetch_add(&g_rdr[b], 1, __ATOMIC_ACQ_REL,
                                             __HIP_MEMORY_SCOPE_AGENT);
            lastflag = (old == 255);
        }
        __syncthreads();
        if (lastflag) {
            // Last reader for this b: reset state for the next launch.
            for (int i = t; i < E_; i += 256)
                __hip_atomic_store(&g_o[b][i], 0.f, __ATOMIC_RELAXED,
                                   __HIP_MEMORY_SCOPE_AGENT);
            __threadfence();
            __syncthreads();
            if (t == 0) {
                __hip_atomic_store(&g_rdr[b], 0, __ATOMIC_RELAXED,
                                   __HIP_MEMORY_SCOPE_AGENT);
                __hip_atomic_store(&g_prog[b], 0, __ATOMIC_RELAXED,
                                   __HIP_MEMORY_SCOPE_AGENT);
            }
        }
    }
}

// ---------------------------------------------------------------------------
extern "C" void kernel_launch(void* const* d_in, const int* in_sizes, int n_in,
                              void* d_out, int out_size, void* d_ws, size_t ws_size,
                              hipStream_t stream) {
    // setup_inputs order: query, key, value, Wq, bq, Wk, bk, Wv, bv, Wo, bo
    const float* value = (const float*)d_in[2];
    const float* Wv    = (const float*)d_in[7];
    const float* bv    = (const float*)d_in[8];
    const float* Wo    = (const float*)d_in[9];
    const float* bo    = (const float*)d_in[10];
    float* out = (float*)d_out;

    float* tpart = (float*)d_ws;                 // [128][B][E]  2 MB

    k_front<<<dim3(ES, SC, B_), 512, 0, stream>>>(value, Wv, tpart);
    k_back <<<dim3(MIDB + BCB), 256, 0, stream>>>(tpart, bv, Wo, bo, out);
}

// Round 9
// 27.128 us; speedup vs baseline: 3.2843x; 3.2843x over previous
//
#include <hip/hip_runtime.h>
#include <hip/hip_bf16.h>

// Problem constants
#define B_ 4
#define S_ 2048
#define E_ 1024

// K1 tiling (round-6 proven geometry)
#define ES 16                 // e-slices of 64
#define SC 4                  // s-chunks of 512
#define EPS (E_ / ES)         // 64 e's per slice
#define SPC (S_ / SC)         // 512 rows per chunk
#define NPART (ES * SC)       // 64 t-partials per batch

// K3 tiling
#define RPB 8                 // rows written per broadcast block

// ---------------------------------------------------------------------------
// K1: fused colsum + GEMV1 split-k, with Wv register prefetch overlapping
// the LDS reduction (Wv loads have no in-block dependency).
// Block (es, sc, b), 1024 threads:
//   vb[64] = colsum over 512 rows of value[b][s][e-slice]
//   tpart[es*SC+sc][b][j] = sum_{e in slice} vb[e] * Wv[e][j]   (plain store)
// Block (0,0,b) also inits o[b][:] = bo[:] for K2's atomics.
// grid (ES, SC, B_) = 256 blocks, 1024 threads.
// ---------------------------------------------------------------------------
__global__ __launch_bounds__(1024) void k_front(const float* __restrict__ value,
                                                const float* __restrict__ Wv,
                                                const float* __restrict__ bo,
                                                float* __restrict__ tpart,
                                                float* __restrict__ o) {
    const int es = blockIdx.x, sc = blockIdx.y, b = blockIdx.z;
    const int t = threadIdx.x;
    __shared__ float4 red[64][16];
    __shared__ float4 red2[4][16];
    __shared__ float vb[EPS];

    // Phase A: column-sum the value tile [512 s][64 e].
    {
        const int c4 = t & 15, rg = t >> 4;
        const float* base = value + ((size_t)b * S_ + (size_t)sc * SPC) * E_
                            + es * EPS + c4 * 4;
        float4 acc = make_float4(0.f, 0.f, 0.f, 0.f);
#pragma unroll
        for (int r = 0; r < 8; ++r) {
            float4 v = *reinterpret_cast<const float4*>(base + (size_t)(rg + r * 64) * E_);
            acc.x += v.x; acc.y += v.y; acc.z += v.z; acc.w += v.w;
        }
        red[rg][c4] = acc;
    }
    __syncthreads();

    // Prefetch this thread's Wv column slice into registers NOW — these
    // loads are independent of the reduction below, so their latency hides
    // under the two LDS-reduce steps.
    float wv_r[EPS];
    {
        const float* wv = Wv + (size_t)(es * EPS) * E_ + t;
#pragma unroll
        for (int k = 0; k < EPS; ++k)
            wv_r[k] = wv[(size_t)k * E_];
    }

    if (t < 64) {
        const int c = t & 15, q = t >> 4;
        float4 s = make_float4(0.f, 0.f, 0.f, 0.f);
#pragma unroll
        for (int k = 0; k < 16; ++k) {
            float4 v = red[q * 16 + k][c];
            s.x += v.x; s.y += v.y; s.z += v.z; s.w += v.w;
        }
        red2[q][c] = s;
    }
    __syncthreads();
    if (t < 16) {
        float4 s0 = red2[0][t], s1 = red2[1][t], s2 = red2[2][t], s3 = red2[3][t];
        float4 s = make_float4(s0.x + s1.x + s2.x + s3.x,
                               s0.y + s1.y + s2.y + s3.y,
                               s0.z + s1.z + s2.z + s3.z,
                               s0.w + s1.w + s2.w + s3.w);
        reinterpret_cast<float4*>(vb)[t] = s;
    }
    __syncthreads();

    // Phase B: pure-FMA t-partial; j = t.
    {
        float a = 0.f;
#pragma unroll
        for (int k = 0; k < EPS; ++k)
            a = fmaf(vb[k], wv_r[k], a);
        tpart[((size_t)(es * SC + sc) * B_ + b) * E_ + t] = a;
    }

    // o init for K2's atomics.
    if (es == 0 && sc == 0 && t < 256) {
        reinterpret_cast<float4*>(o + (size_t)b * E_)[t] =
            reinterpret_cast<const float4*>(bo)[t];
    }
}

// ---------------------------------------------------------------------------
// K2: reduce t-partials + bias, then Wo row-panel -> o via 64-way atomics.
// Block (jb, b): tj[0..15] = S*bv + sum_p tpart[p][b][jb*16..+16];
//                o[b][i] += sum_j tj[j] * Wo[jb*16+j][i]
// grid (64, B_) = 256 blocks, 256 threads.  (byte-identical to round 6)
// ---------------------------------------------------------------------------
__global__ __launch_bounds__(256) void k_mid(const float* __restrict__ tpart,
                                             const float* __restrict__ bv,
                                             const float* __restrict__ Wo,
                                             float* __restrict__ o) {
    const int jb = blockIdx.x, b = blockIdx.y;
    const int t = threadIdx.x;
    __shared__ float red[16][16];
    __shared__ float tj[16];

    {
        const int jl = t & 15, pg = t >> 4;
        float s = 0.f;
#pragma unroll
        for (int q = 0; q < 4; ++q) {
            const int p = pg + q * 16;
            s += tpart[((size_t)p * B_ + b) * E_ + jb * 16 + jl];
        }
        red[pg][jl] = s;
    }
    __syncthreads();
    if (t < 16) {
        float v = (float)S_ * bv[jb * 16 + t];
#pragma unroll
        for (int g = 0; g < 16; ++g) v += red[g][t];
        tj[t] = v;
    }
    __syncthreads();

    float oacc[4] = {0.f, 0.f, 0.f, 0.f};
#pragma unroll
    for (int jj = 0; jj < 16; ++jj) {
        const float* wo = Wo + (size_t)(jb * 16 + jj) * E_;
        const float tv = tj[jj];
#pragma unroll
        for (int k2 = 0; k2 < 4; ++k2)
            oacc[k2] = fmaf(tv, wo[k2 * 256 + t], oacc[k2]);
    }
#pragma unroll
    for (int k2 = 0; k2 < 4; ++k2)
        atomicAdd(&o[(size_t)b * E_ + k2 * 256 + t], oacc[k2]);
}

// ---------------------------------------------------------------------------
// K3: out[b][s][:] = o[b][:]  broadcast over s.
// grid (S_/RPB, B_) = 1024 blocks, 256 threads.  (byte-identical to round 6)
// ---------------------------------------------------------------------------
__global__ __launch_bounds__(256) void k_bcast(const float* __restrict__ o,
                                               float* __restrict__ out) {
    const int sb = blockIdx.x, b = blockIdx.y;
    const int t = threadIdx.x;
    float4 ov = reinterpret_cast<const float4*>(o + (size_t)b * E_)[t];
    float4* dst = reinterpret_cast<float4*>(
        out + ((size_t)b * S_ + (size_t)sb * RPB) * E_);
#pragma unroll
    for (int r = 0; r < RPB; ++r)
        dst[r * (E_ / 4) + t] = ov;
}

// ---------------------------------------------------------------------------
extern "C" void kernel_launch(void* const* d_in, const int* in_sizes, int n_in,
                              void* d_out, int out_size, void* d_ws, size_t ws_size,
                              hipStream_t stream) {
    // setup_inputs order: query, key, value, Wq, bq, Wk, bk, Wv, bv, Wo, bo
    const float* value = (const float*)d_in[2];
    const float* Wv    = (const float*)d_in[7];
    const float* bv    = (const float*)d_in[8];
    const float* Wo    = (const float*)d_in[9];
    const float* bo    = (const float*)d_in[10];
    float* out = (float*)d_out;

    float* tpart = (float*)d_ws;                       // [64][B][E]  1 MB
    float* o     = tpart + (size_t)NPART * B_ * E_;    // [B][E]      16 KB

    k_front<<<dim3(ES, SC, B_),    1024, 0, stream>>>(value, Wv, bo, tpart, o);
    k_mid  <<<dim3(NPART, B_),     256,  0, stream>>>(tpart, bv, Wo, o);
    k_bcast<<<dim3(S_ / RPB, B_),  256,  0, stream>>>(o, out);
}